// Round 1
// baseline (841.632 us; speedup 1.0000x reference)
//
#include <hip/hip_runtime.h>
#include <hip/hip_bf16.h>

#define N_NODES 100000
#define N_EDGES 3200000

typedef short v8s __attribute__((ext_vector_type(8)));
typedef float v4f __attribute__((ext_vector_type(4)));

__device__ __forceinline__ unsigned short f2b(float x) {
    __hip_bfloat16 h = __float2bfloat16(x);
    return *reinterpret_cast<unsigned short*>(&h);
}
__device__ __forceinline__ float b2f(unsigned short u) {
    return __uint_as_float(((unsigned int)u) << 16);
}

// ---------------------------------------------------------------------------
// Pre-transpose + convert weight: B[k][n] fp32 -> BT[n][k] bf16
// ---------------------------------------------------------------------------
__global__ void transpose_b(const float* __restrict__ B, unsigned short* __restrict__ BT) {
    int n = blockIdx.x;
    int k = threadIdx.x;
    BT[n * 256 + k] = f2b(B[k * 256 + n]);
}

// ---------------------------------------------------------------------------
// GEMM: support[m][n] = sum_k A[m][k] * W[k][n], bf16 MFMA, bf16 output.
// Block = 256 threads (4 waves). Tile: 64 (M) x 256 (N full). BK = 32.
// Each wave owns 16 M-rows x 256 N (16 MFMA tiles of 16x16x32).
// A staged fp32->bf16 inline; B staged from pre-transposed bf16 BT[n][k].
// ---------------------------------------------------------------------------
#define LDA_PAD 40   // bf16 elems per LDS row (32 + 8 pad) -> 80B row stride
#define LDB_PAD 40

__global__ __launch_bounds__(256)
void gemm_kernel(const float* __restrict__ A, const unsigned short* __restrict__ BT,
                 unsigned short* __restrict__ C) {
    __shared__ __align__(16) unsigned short sA[64 * LDA_PAD];    // [m][k]
    __shared__ __align__(16) unsigned short sBT[256 * LDB_PAD];  // [n][k]

    const int tid  = threadIdx.x;
    const int wave = tid >> 6;
    const int lane = tid & 63;
    const int quad = lane >> 4;
    const int l16  = lane & 15;
    const int mtile = blockIdx.x * 64;

    v4f acc[16];
#pragma unroll
    for (int t = 0; t < 16; t++) acc[t] = (v4f){0.f, 0.f, 0.f, 0.f};

    for (int k0 = 0; k0 < 256; k0 += 32) {
        // --- stage A: 64 rows x 32 k = 512 float4, 2 per thread ---
#pragma unroll
        for (int i = 0; i < 2; i++) {
            int f  = tid + i * 256;
            int k4 = f & 7;       // float4 index within the 32-wide k chunk
            int m  = f >> 3;
            int grow = mtile + m;
            float4 v = make_float4(0.f, 0.f, 0.f, 0.f);
            if (grow < N_NODES)
                v = ((const float4*)(A + (size_t)grow * 256 + k0))[k4];
            ushort4 h;
            h.x = f2b(v.x); h.y = f2b(v.y); h.z = f2b(v.z); h.w = f2b(v.w);
            *(ushort4*)(&sA[m * LDA_PAD + k4 * 4]) = h;   // 8B write, aligned
        }
        // --- stage B: 256 n-rows x 32 k bf16 = 1024 x 16B, 4 per thread ---
#pragma unroll
        for (int i = 0; i < 4; i++) {
            int f  = tid + i * 256;
            int kq = f & 3;       // which 8-elem (16B) chunk of the 32 k
            int n  = f >> 2;
            v8s b = *(const v8s*)(BT + (size_t)n * 256 + k0 + kq * 8);
            *(v8s*)(&sBT[n * LDB_PAD + kq * 8]) = b;      // 16B write, aligned
        }
        __syncthreads();

        // --- fragments + MFMA ---
        // A operand: A[m = lane&15][k = quad*8 + j]
        v8s a = *(const v8s*)(&sA[(wave * 16 + l16) * LDA_PAD + quad * 8]);
#pragma unroll
        for (int t = 0; t < 16; t++) {
            // B operand: B[k = quad*8 + j][n = lane&15] == sBT[n][k]
            int n = t * 16 + l16;
            v8s b = *(const v8s*)(&sBT[n * LDB_PAD + quad * 8]);
            acc[t] = __builtin_amdgcn_mfma_f32_16x16x32_bf16(a, b, acc[t], 0, 0, 0);
        }
        __syncthreads();
    }

    // --- epilogue: D mapping col = lane&15, row = quad*4 + reg ---
    const int grow_base = mtile + wave * 16 + quad * 4;
#pragma unroll
    for (int t = 0; t < 16; t++) {
#pragma unroll
        for (int r = 0; r < 4; r++) {
            int grow = grow_base + r;
            if (grow < N_NODES) {
                int gcol = t * 16 + l16;
                C[(size_t)grow * 256 + gcol] = f2b(acc[t][r]);
            }
        }
    }
}

// ---------------------------------------------------------------------------
// CSR construction: histogram -> 3-kernel exclusive scan -> fill
// ---------------------------------------------------------------------------
__global__ void hist_kernel(const int* __restrict__ row, int* __restrict__ counts) {
    int e = blockIdx.x * 256 + threadIdx.x;
    if (e < N_EDGES) atomicAdd(&counts[row[e]], 1);
}

__global__ void scan1(const int* __restrict__ counts, int* __restrict__ offs,
                      int* __restrict__ partials) {
    __shared__ int s[256];
    int tid = threadIdx.x;
    int g = blockIdx.x * 256 + tid;
    int x = (g < N_NODES) ? counts[g] : 0;
    s[tid] = x;
    __syncthreads();
    for (int off = 1; off < 256; off <<= 1) {
        int v = (tid >= off) ? s[tid - off] : 0;
        __syncthreads();
        s[tid] += v;
        __syncthreads();
    }
    if (g < N_NODES) offs[g] = s[tid] - x;        // exclusive within block
    if (tid == 255) partials[blockIdx.x] = s[255]; // block total
}

__global__ void scan2(int* __restrict__ partials) {
    __shared__ int s[512];
    int tid = threadIdx.x;
    int x = (tid < 391) ? partials[tid] : 0;
    s[tid] = x;
    __syncthreads();
    for (int off = 1; off < 512; off <<= 1) {
        int v = (tid >= off) ? s[tid - off] : 0;
        __syncthreads();
        s[tid] += v;
        __syncthreads();
    }
    if (tid < 391) partials[tid] = s[tid] - x;     // exclusive
}

__global__ void scan3(const int* __restrict__ partials, int* __restrict__ offs,
                      int* __restrict__ cursor) {
    int g = blockIdx.x * 256 + threadIdx.x;
    if (g < N_NODES) {
        int o = offs[g] + partials[blockIdx.x];
        offs[g] = o;
        cursor[g] = o;
    }
}

__global__ void fill_kernel(const int* __restrict__ row, const int* __restrict__ col,
                            const float* __restrict__ val, int* __restrict__ cursor,
                            int2* __restrict__ csr) {
    int e = blockIdx.x * 256 + threadIdx.x;
    if (e >= N_EDGES) return;
    int r = row[e];
    int p = atomicAdd(&cursor[r], 1);
    csr[p] = make_int2(col[e], __float_as_int(val[e]));
}

// ---------------------------------------------------------------------------
// SpMM: one wave per row. Each lane owns 4 consecutive output dims (lane*4).
// Gather support rows (bf16, 8B/lane), accumulate fp32, write row once + ReLU.
// ---------------------------------------------------------------------------
__global__ __launch_bounds__(256)
void spmm_kernel(const unsigned short* __restrict__ sup,
                 const int* __restrict__ offs, const int* __restrict__ counts,
                 const int2* __restrict__ csr, float* __restrict__ out) {
    const int wave = threadIdx.x >> 6;
    const int lane = threadIdx.x & 63;
    const int row  = blockIdx.x * 4 + wave;
    if (row >= N_NODES) return;

    const int start = offs[row];
    const int deg   = counts[row];

    float a0 = 0.f, a1 = 0.f, a2 = 0.f, a3 = 0.f;

    for (int base = 0; base < deg; base += 64) {
        int n = deg - base;
        if (n > 64) n = 64;
        int c = 0;
        float v = 0.f;
        if (lane < n) {
            int2 t = csr[start + base + lane];
            c = t.x;
            v = __int_as_float(t.y);
        }
        for (int j = 0; j < n; j++) {
            int   cj = __shfl(c, j);
            float vj = __shfl(v, j);
            ushort4 h = *(const ushort4*)(sup + (size_t)cj * 256 + lane * 4);
            a0 += vj * b2f(h.x);
            a1 += vj * b2f(h.y);
            a2 += vj * b2f(h.z);
            a3 += vj * b2f(h.w);
        }
    }

    float4 o;
    o.x = a0 > 0.f ? a0 : 0.f;
    o.y = a1 > 0.f ? a1 : 0.f;
    o.z = a2 > 0.f ? a2 : 0.f;
    o.w = a3 > 0.f ? a3 : 0.f;
    *(float4*)(out + (size_t)row * 256 + lane * 4) = o;
}

// ---------------------------------------------------------------------------
extern "C" void kernel_launch(void* const* d_in, const int* in_sizes, int n_in,
                              void* d_out, int out_size, void* d_ws, size_t ws_size,
                              hipStream_t stream) {
    const float* features = (const float*)d_in[0];
    const float* weight   = (const float*)d_in[1];
    const int*   adj_row  = (const int*)d_in[2];
    const int*   adj_col  = (const int*)d_in[3];
    const float* adj_val  = (const float*)d_in[4];
    float* out = (float*)d_out;

    char* ws = (char*)d_ws;
    size_t off = 0;
    auto alloc = [&](size_t bytes) -> char* {
        char* p = ws + off;
        off = (off + bytes + 255) & ~(size_t)255;
        return p;
    };
    unsigned short* sup      = (unsigned short*)alloc((size_t)N_NODES * 256 * 2); // 51.2 MB
    unsigned short* BT       = (unsigned short*)alloc(256 * 256 * 2);
    int*            counts   = (int*)alloc((size_t)N_NODES * 4);
    int*            offsets  = (int*)alloc((size_t)N_NODES * 4);
    int*            cursor   = (int*)alloc((size_t)N_NODES * 4);
    int*            partials = (int*)alloc(512 * 4);
    int2*           csr      = (int2*)alloc((size_t)N_EDGES * 8);                 // 25.6 MB

    hipMemsetAsync(counts, 0, (size_t)N_NODES * 4, stream);

    transpose_b<<<256, 256, 0, stream>>>(weight, BT);
    gemm_kernel<<<1563, 256, 0, stream>>>(features, BT, sup);   // ceil(100000/64)
    hist_kernel<<<12500, 256, 0, stream>>>(adj_row, counts);
    scan1<<<391, 256, 0, stream>>>(counts, offsets, partials);
    scan2<<<1, 512, 0, stream>>>(partials);
    scan3<<<391, 256, 0, stream>>>(partials, offsets, cursor);
    fill_kernel<<<12500, 256, 0, stream>>>(adj_row, adj_col, adj_val, cursor, csr);
    spmm_kernel<<<25000, 256, 0, stream>>>(sup, offsets, counts, csr, out);
}

// Round 2
// 566.517 us; speedup vs baseline: 1.4856x; 1.4856x over previous
//
#include <hip/hip_runtime.h>
#include <hip/hip_bf16.h>

#define N_NODES 100000
#define N_EDGES 3200000
#define NBUCK   391          // ceil(100000 / 256) buckets of 256 rows

typedef short v8s __attribute__((ext_vector_type(8)));
typedef float v4f __attribute__((ext_vector_type(4)));

__device__ __forceinline__ unsigned short f2b(float x) {
    __hip_bfloat16 h = __float2bfloat16(x);
    return *reinterpret_cast<unsigned short*>(&h);
}
__device__ __forceinline__ float b2f(unsigned short u) {
    return __uint_as_float(((unsigned int)u) << 16);
}

// ---------------------------------------------------------------------------
// Pre-transpose + convert weight: B[k][n] fp32 -> BT[n][k] bf16
// ---------------------------------------------------------------------------
__global__ void transpose_b(const float* __restrict__ B, unsigned short* __restrict__ BT) {
    int n = blockIdx.x;
    int k = threadIdx.x;
    BT[n * 256 + k] = f2b(B[k * 256 + n]);
}

// ---------------------------------------------------------------------------
// GEMM: support[m][n] = sum_k A[m][k] * W[k][n], bf16 MFMA, bf16 output.
// (unchanged from R1 for attribution)
// ---------------------------------------------------------------------------
#define LDA_PAD 40
#define LDB_PAD 40

__global__ __launch_bounds__(256)
void gemm_kernel(const float* __restrict__ A, const unsigned short* __restrict__ BT,
                 unsigned short* __restrict__ C) {
    __shared__ __align__(16) unsigned short sA[64 * LDA_PAD];    // [m][k]
    __shared__ __align__(16) unsigned short sBT[256 * LDB_PAD];  // [n][k]

    const int tid  = threadIdx.x;
    const int wave = tid >> 6;
    const int lane = tid & 63;
    const int quad = lane >> 4;
    const int l16  = lane & 15;
    const int mtile = blockIdx.x * 64;

    v4f acc[16];
#pragma unroll
    for (int t = 0; t < 16; t++) acc[t] = (v4f){0.f, 0.f, 0.f, 0.f};

    for (int k0 = 0; k0 < 256; k0 += 32) {
#pragma unroll
        for (int i = 0; i < 2; i++) {
            int f  = tid + i * 256;
            int k4 = f & 7;
            int m  = f >> 3;
            int grow = mtile + m;
            float4 v = make_float4(0.f, 0.f, 0.f, 0.f);
            if (grow < N_NODES)
                v = ((const float4*)(A + (size_t)grow * 256 + k0))[k4];
            ushort4 h;
            h.x = f2b(v.x); h.y = f2b(v.y); h.z = f2b(v.z); h.w = f2b(v.w);
            *(ushort4*)(&sA[m * LDA_PAD + k4 * 4]) = h;
        }
#pragma unroll
        for (int i = 0; i < 4; i++) {
            int f  = tid + i * 256;
            int kq = f & 3;
            int n  = f >> 2;
            v8s b = *(const v8s*)(BT + (size_t)n * 256 + k0 + kq * 8);
            *(v8s*)(&sBT[n * LDB_PAD + kq * 8]) = b;
        }
        __syncthreads();

        v8s a = *(const v8s*)(&sA[(wave * 16 + l16) * LDA_PAD + quad * 8]);
#pragma unroll
        for (int t = 0; t < 16; t++) {
            int n = t * 16 + l16;
            v8s b = *(const v8s*)(&sBT[n * LDB_PAD + quad * 8]);
            acc[t] = __builtin_amdgcn_mfma_f32_16x16x32_bf16(a, b, acc[t], 0, 0, 0);
        }
        __syncthreads();
    }

    const int grow_base = mtile + wave * 16 + quad * 4;
#pragma unroll
    for (int t = 0; t < 16; t++) {
#pragma unroll
        for (int r = 0; r < 4; r++) {
            int grow = grow_base + r;
            if (grow < N_NODES) {
                int gcol = t * 16 + l16;
                C[(size_t)grow * 256 + gcol] = f2b(acc[t][r]);
            }
        }
    }
}

// ---------------------------------------------------------------------------
// Coarse histogram over 391 buckets (rows >> 8) with LDS pre-aggregation.
// ---------------------------------------------------------------------------
__global__ __launch_bounds__(256)
void bhist_kernel(const int* __restrict__ row, int* __restrict__ ghist) {
    __shared__ int h[NBUCK];
    const int tid = threadIdx.x;
    for (int i = tid; i < NBUCK; i += 256) h[i] = 0;
    __syncthreads();
    const int e0 = blockIdx.x * 4096;
#pragma unroll
    for (int j = 0; j < 16; j++) {
        int e = e0 + j * 256 + tid;
        if (e < N_EDGES) atomicAdd(&h[row[e] >> 8], 1);
    }
    __syncthreads();
    for (int i = tid; i < NBUCK; i += 256)
        if (h[i]) atomicAdd(&ghist[i], h[i]);
}

// Exclusive scan of 391 bucket counts; also initializes the global cursors.
__global__ void bscan_kernel(const int* __restrict__ ghist, int* __restrict__ bbase,
                             int* __restrict__ gcur) {
    __shared__ int s[512];
    const int tid = threadIdx.x;   // 512 threads
    int x = (tid < NBUCK) ? ghist[tid] : 0;
    s[tid] = x;
    __syncthreads();
    for (int off = 1; off < 512; off <<= 1) {
        int v = (tid >= off) ? s[tid - off] : 0;
        __syncthreads();
        s[tid] += v;
        __syncthreads();
    }
    if (tid < NBUCK) {
        int b = s[tid] - x;
        bbase[tid] = b;
        gcur[tid]  = b;
    }
}

// ---------------------------------------------------------------------------
// Bin pass: scatter edges into 391 bucket regions, block-coherent writes.
// Entry: .x = (row_local<<20)|col, .y = fp32 val bits.
// ---------------------------------------------------------------------------
__global__ __launch_bounds__(256)
void bin_kernel(const int* __restrict__ row, const int* __restrict__ col,
                const float* __restrict__ val, int* __restrict__ gcur,
                int2* __restrict__ bucket) {
    __shared__ int lc[NBUCK];
    const int tid = threadIdx.x;
    const int e0 = blockIdx.x * 4096;
    int r[16], c[16];
    float v[16];
#pragma unroll
    for (int j = 0; j < 16; j++) {
        int e = e0 + j * 256 + tid;
        if (e < N_EDGES) { r[j] = row[e]; c[j] = col[e]; v[j] = val[e]; }
        else r[j] = -1;
    }
    for (int i = tid; i < NBUCK; i += 256) lc[i] = 0;
    __syncthreads();
#pragma unroll
    for (int j = 0; j < 16; j++)
        if (r[j] >= 0) atomicAdd(&lc[r[j] >> 8], 1);
    __syncthreads();
    for (int i = tid; i < NBUCK; i += 256) {
        int cnt = lc[i];
        lc[i] = cnt ? atomicAdd(&gcur[i], cnt) : 0;
    }
    __syncthreads();
#pragma unroll
    for (int j = 0; j < 16; j++) {
        if (r[j] >= 0) {
            int b = r[j] >> 8;
            int p = atomicAdd(&lc[b], 1);
            bucket[p] = make_int2(((r[j] & 255) << 20) | c[j], __float_as_int(v[j]));
        }
    }
}

// ---------------------------------------------------------------------------
// Per-bucket counting sort into final CSR (4B packed entries) + offs/counts.
// ---------------------------------------------------------------------------
__global__ __launch_bounds__(256)
void csort_kernel(const int2* __restrict__ bucket, const int* __restrict__ bbase,
                  const int* __restrict__ gcur, unsigned int* __restrict__ csr,
                  int* __restrict__ offs, int* __restrict__ counts) {
    __shared__ int h[256];
    __shared__ int s[256];
    __shared__ int cur[256];
    const int tid  = threadIdx.x;
    const int b    = blockIdx.x;
    const int base = bbase[b];
    const int end  = gcur[b];          // after bin pass: base + bucket size

    h[tid] = 0;
    __syncthreads();
    for (int i = base + tid; i < end; i += 256)
        atomicAdd(&h[bucket[i].x >> 20], 1);
    __syncthreads();

    int x = h[tid];
    s[tid] = x;
    __syncthreads();
    for (int off = 1; off < 256; off <<= 1) {
        int v2 = (tid >= off) ? s[tid - off] : 0;
        __syncthreads();
        s[tid] += v2;
        __syncthreads();
    }
    int ro = s[tid] - x;               // exclusive offset within bucket
    int grow = b * 256 + tid;
    if (grow < N_NODES) {
        offs[grow]   = base + ro;
        counts[grow] = x;
    }
    cur[tid] = base + ro;
    __syncthreads();

    for (int i = base + tid; i < end; i += 256) {
        int2 w = bucket[i];
        int rl = w.x >> 20;
        int p  = atomicAdd(&cur[rl], 1);
        unsigned int vb = (((unsigned int)w.y + 0x8000u) >> 16) & 0x7FFFu;
        csr[p] = (vb << 17) | (unsigned int)(w.x & 0x1FFFF);
    }
}

// ---------------------------------------------------------------------------
// SpMM: one wave per row (CSR entry now 4B packed).
// ---------------------------------------------------------------------------
__global__ __launch_bounds__(256)
void spmm_kernel(const unsigned short* __restrict__ sup,
                 const int* __restrict__ offs, const int* __restrict__ counts,
                 const unsigned int* __restrict__ csr, float* __restrict__ out) {
    const int wave = threadIdx.x >> 6;
    const int lane = threadIdx.x & 63;
    const int row  = blockIdx.x * 4 + wave;
    if (row >= N_NODES) return;

    const int start = offs[row];
    const int deg   = counts[row];

    float a0 = 0.f, a1 = 0.f, a2 = 0.f, a3 = 0.f;

    for (int base = 0; base < deg; base += 64) {
        int n = deg - base;
        if (n > 64) n = 64;
        int c = 0;
        float v = 0.f;
        if (lane < n) {
            unsigned int w = csr[start + base + lane];
            c = (int)(w & 0x1FFFFu);
            v = __uint_as_float((w >> 17) << 16);
        }
        for (int j = 0; j < n; j++) {
            int   cj = __shfl(c, j);
            float vj = __shfl(v, j);
            ushort4 hh = *(const ushort4*)(sup + (size_t)cj * 256 + lane * 4);
            a0 += vj * b2f(hh.x);
            a1 += vj * b2f(hh.y);
            a2 += vj * b2f(hh.z);
            a3 += vj * b2f(hh.w);
        }
    }

    float4 o;
    o.x = a0 > 0.f ? a0 : 0.f;
    o.y = a1 > 0.f ? a1 : 0.f;
    o.z = a2 > 0.f ? a2 : 0.f;
    o.w = a3 > 0.f ? a3 : 0.f;
    *(float4*)(out + (size_t)row * 256 + lane * 4) = o;
}

// ---------------------------------------------------------------------------
extern "C" void kernel_launch(void* const* d_in, const int* in_sizes, int n_in,
                              void* d_out, int out_size, void* d_ws, size_t ws_size,
                              hipStream_t stream) {
    const float* features = (const float*)d_in[0];
    const float* weight   = (const float*)d_in[1];
    const int*   adj_row  = (const int*)d_in[2];
    const int*   adj_col  = (const int*)d_in[3];
    const float* adj_val  = (const float*)d_in[4];
    float* out = (float*)d_out;

    char* ws = (char*)d_ws;
    size_t off = 0;
    auto alloc = [&](size_t bytes) -> char* {
        char* p = ws + off;
        off = (off + bytes + 255) & ~(size_t)255;
        return p;
    };
    unsigned short* sup     = (unsigned short*)alloc((size_t)N_NODES * 256 * 2); // 51.2 MB
    unsigned short* BT      = (unsigned short*)alloc(256 * 256 * 2);
    int*            counts  = (int*)alloc((size_t)N_NODES * 4);
    int*            offsets = (int*)alloc((size_t)N_NODES * 4);
    int*            ghist   = (int*)alloc(512 * 4);
    int*            bbase   = (int*)alloc(512 * 4);
    int*            gcur    = (int*)alloc(512 * 4);
    int2*           bucket  = (int2*)alloc((size_t)N_EDGES * 8);                 // 25.6 MB
    unsigned int*   csr     = (unsigned int*)alloc((size_t)N_EDGES * 4);         // 12.8 MB

    hipMemsetAsync(ghist, 0, NBUCK * 4, stream);

    transpose_b<<<256, 256, 0, stream>>>(weight, BT);
    gemm_kernel<<<1563, 256, 0, stream>>>(features, BT, sup);      // ceil(100000/64)
    bhist_kernel<<<782, 256, 0, stream>>>(adj_row, ghist);         // ceil(3.2M/4096)
    bscan_kernel<<<1, 512, 0, stream>>>(ghist, bbase, gcur);
    bin_kernel<<<782, 256, 0, stream>>>(adj_row, adj_col, adj_val, gcur, bucket);
    csort_kernel<<<NBUCK, 256, 0, stream>>>(bucket, bbase, gcur, csr, offsets, counts);
    spmm_kernel<<<25000, 256, 0, stream>>>(sup, offsets, counts, csr, out);
}

// Round 3
// 539.614 us; speedup vs baseline: 1.5597x; 1.0499x over previous
//
#include <hip/hip_runtime.h>
#include <hip/hip_bf16.h>

#define N_NODES 100000
#define N_EDGES 3200000
#define NBUCK   391          // ceil(100000 / 256) buckets of 256 rows

typedef short v8s __attribute__((ext_vector_type(8)));
typedef float v4f __attribute__((ext_vector_type(4)));

__device__ __forceinline__ unsigned short f2b(float x) {
    __hip_bfloat16 h = __float2bfloat16(x);
    return *reinterpret_cast<unsigned short*>(&h);
}
__device__ __forceinline__ float b2f(unsigned short u) {
    return __uint_as_float(((unsigned int)u) << 16);
}

// async global->LDS, 16B per lane. LDS dest is wave-uniform base + lane*16,
// so LDS layout must be slot-contiguous in lane order (we XOR-swizzle the
// GLOBAL side instead, since the LDS side can't be padded).
__device__ __forceinline__ void gld16(const void* g, void* l) {
    __builtin_amdgcn_global_load_lds(
        (const __attribute__((address_space(1))) void*)g,
        (__attribute__((address_space(3))) void*)l, 16, 0, 0);
}

// ---------------------------------------------------------------------------
// Pre-transpose + convert weight: B[k][n] fp32 -> BT[n][k] bf16
// ---------------------------------------------------------------------------
__global__ void transpose_b(const float* __restrict__ B, unsigned short* __restrict__ BT) {
    int n = blockIdx.x;
    int k = threadIdx.x;
    BT[n * 256 + k] = f2b(B[k * 256 + n]);
}

// ---------------------------------------------------------------------------
// GEMM v2 (m97-style): 128x256 tile, 512 threads (8 waves x 16 rows), BK=64,
// global_load_lds(16B) staging for A (fp32, cvt at frag read) and B (bf16).
// XOR-swizzled chunk layouts -> 2-way max LDS bank aliasing (free).
//   sA: 128 rows x 16 chunks(4 fp32): slot(m,c) = m*16 + (c ^ (m&15))
//   sB: 256 rows x  8 chunks(8 bf16): slot(n,c) = n*8  + (c ^ (n&7))
// ---------------------------------------------------------------------------
__global__ __launch_bounds__(512)
void gemm_dma(const float* __restrict__ A, const unsigned short* __restrict__ BT,
              unsigned short* __restrict__ C) {
    __shared__ __align__(16) float          sA[128 * 64];   // 32 KB
    __shared__ __align__(16) unsigned short sB[256 * 64];   // 32 KB

    const int tid  = threadIdx.x;
    const int wave = tid >> 6;
    const int lane = tid & 63;
    const int quad = lane >> 4;
    const int l16  = lane & 15;
    const int row0 = blockIdx.x * 128;

    v4f acc[16];
#pragma unroll
    for (int t = 0; t < 16; t++) acc[t] = (v4f){0.f, 0.f, 0.f, 0.f};

    const int ml = wave * 16 + l16;            // this lane's A row (local)

    for (int ks = 0; ks < 4; ks++) {
        const int kbase = ks * 64;
        // --- stage A: 128 x 64 fp32 = 2048 x 16B chunks ---
#pragma unroll
        for (int i = 0; i < 4; i++) {
            int s = i * 512 + tid;
            int m = s >> 4;
            int c = (s & 15) ^ (m & 15);
            int row = row0 + m;
            if (row >= N_NODES) row = row0;    // clamp (stores are guarded)
            gld16(A + (size_t)row * 256 + kbase + c * 4, (char*)sA + (size_t)s * 16);
        }
        // --- stage B: 256 x 64 bf16 = 2048 x 16B chunks ---
#pragma unroll
        for (int i = 0; i < 4; i++) {
            int s = i * 512 + tid;
            int n = s >> 3;
            int c = (s & 7) ^ (n & 7);
            gld16(BT + (size_t)n * 256 + kbase + c * 8, (char*)sB + (size_t)s * 16);
        }
        __syncthreads();

#pragma unroll
        for (int sub = 0; sub < 2; sub++) {
            // A fragment: 8 fp32 at k = sub*32 + quad*8, swizzled chunk pair
            int ca  = sub * 8 + 2 * quad;
            int pa0 = ml * 16 + (ca ^ (ml & 15));
            int pa1 = ml * 16 + ((ca + 1) ^ (ml & 15));
            v4f lo = *(const v4f*)&sA[pa0 * 4];
            v4f hi = *(const v4f*)&sA[pa1 * 4];
            v8s af;
            af[0] = (short)f2b(lo[0]); af[1] = (short)f2b(lo[1]);
            af[2] = (short)f2b(lo[2]); af[3] = (short)f2b(lo[3]);
            af[4] = (short)f2b(hi[0]); af[5] = (short)f2b(hi[1]);
            af[6] = (short)f2b(hi[2]); af[7] = (short)f2b(hi[3]);
            int cb = sub * 4 + quad;
#pragma unroll
            for (int t = 0; t < 16; t++) {
                int n  = t * 16 + l16;
                int pb = n * 8 + (cb ^ (n & 7));
                v8s bf = *(const v8s*)&sB[pb * 8];
                acc[t] = __builtin_amdgcn_mfma_f32_16x16x32_bf16(af, bf, acc[t], 0, 0, 0);
            }
        }
        __syncthreads();
    }

    // epilogue: D mapping col = l16, row = quad*4 + reg
    const int grow_base = row0 + wave * 16 + quad * 4;
#pragma unroll
    for (int t = 0; t < 16; t++) {
#pragma unroll
        for (int r = 0; r < 4; r++) {
            int grow = grow_base + r;
            if (grow < N_NODES)
                C[(size_t)grow * 256 + t * 16 + l16] = f2b(acc[t][r]);
        }
    }
}

// ---------------------------------------------------------------------------
// Coarse histogram over 391 buckets (rows >> 8) with LDS pre-aggregation.
// ---------------------------------------------------------------------------
__global__ __launch_bounds__(256)
void bhist_kernel(const int* __restrict__ row, int* __restrict__ ghist) {
    __shared__ int h[NBUCK];
    const int tid = threadIdx.x;
    for (int i = tid; i < NBUCK; i += 256) h[i] = 0;
    __syncthreads();
    const int e0 = blockIdx.x * 4096;
#pragma unroll
    for (int j = 0; j < 16; j++) {
        int e = e0 + j * 256 + tid;
        if (e < N_EDGES) atomicAdd(&h[row[e] >> 8], 1);
    }
    __syncthreads();
    for (int i = tid; i < NBUCK; i += 256)
        if (h[i]) atomicAdd(&ghist[i], h[i]);
}

// Exclusive scan of 391 bucket counts; also initializes the global cursors.
__global__ void bscan_kernel(const int* __restrict__ ghist, int* __restrict__ bbase,
                             int* __restrict__ gcur) {
    __shared__ int s[512];
    const int tid = threadIdx.x;   // 512 threads
    int x = (tid < NBUCK) ? ghist[tid] : 0;
    s[tid] = x;
    __syncthreads();
    for (int off = 1; off < 512; off <<= 1) {
        int v = (tid >= off) ? s[tid - off] : 0;
        __syncthreads();
        s[tid] += v;
        __syncthreads();
    }
    if (tid < NBUCK) {
        int b = s[tid] - x;
        bbase[tid] = b;
        gcur[tid]  = b;
    }
}

// ---------------------------------------------------------------------------
// Bin pass: scatter edges into 391 bucket regions, block-coherent writes.
// Entry: .x = (row_local<<20)|col, .y = fp32 val bits.
// ---------------------------------------------------------------------------
__global__ __launch_bounds__(256)
void bin_kernel(const int* __restrict__ row, const int* __restrict__ col,
                const float* __restrict__ val, int* __restrict__ gcur,
                int2* __restrict__ bucket) {
    __shared__ int lc[NBUCK];
    const int tid = threadIdx.x;
    const int e0 = blockIdx.x * 4096;
    int r[16], c[16];
    float v[16];
#pragma unroll
    for (int j = 0; j < 16; j++) {
        int e = e0 + j * 256 + tid;
        if (e < N_EDGES) { r[j] = row[e]; c[j] = col[e]; v[j] = val[e]; }
        else r[j] = -1;
    }
    for (int i = tid; i < NBUCK; i += 256) lc[i] = 0;
    __syncthreads();
#pragma unroll
    for (int j = 0; j < 16; j++)
        if (r[j] >= 0) atomicAdd(&lc[r[j] >> 8], 1);
    __syncthreads();
    for (int i = tid; i < NBUCK; i += 256) {
        int cnt = lc[i];
        lc[i] = cnt ? atomicAdd(&gcur[i], cnt) : 0;
    }
    __syncthreads();
#pragma unroll
    for (int j = 0; j < 16; j++) {
        if (r[j] >= 0) {
            int b = r[j] >> 8;
            int p = atomicAdd(&lc[b], 1);
            bucket[p] = make_int2(((r[j] & 255) << 20) | c[j], __float_as_int(v[j]));
        }
    }
}

// ---------------------------------------------------------------------------
// Per-bucket counting sort into final CSR (4B packed entries) + offs/counts.
// ---------------------------------------------------------------------------
__global__ __launch_bounds__(256)
void csort_kernel(const int2* __restrict__ bucket, const int* __restrict__ bbase,
                  const int* __restrict__ gcur, unsigned int* __restrict__ csr,
                  int* __restrict__ offs, int* __restrict__ counts) {
    __shared__ int h[256];
    __shared__ int s[256];
    __shared__ int cur[256];
    const int tid  = threadIdx.x;
    const int b    = blockIdx.x;
    const int base = bbase[b];
    const int end  = gcur[b];          // after bin pass: base + bucket size

    h[tid] = 0;
    __syncthreads();
    for (int i = base + tid; i < end; i += 256)
        atomicAdd(&h[bucket[i].x >> 20], 1);
    __syncthreads();

    int x = h[tid];
    s[tid] = x;
    __syncthreads();
    for (int off = 1; off < 256; off <<= 1) {
        int v2 = (tid >= off) ? s[tid - off] : 0;
        __syncthreads();
        s[tid] += v2;
        __syncthreads();
    }
    int ro = s[tid] - x;               // exclusive offset within bucket
    int grow = b * 256 + tid;
    if (grow < N_NODES) {
        offs[grow]   = base + ro;
        counts[grow] = x;
    }
    cur[tid] = base + ro;
    __syncthreads();

    for (int i = base + tid; i < end; i += 256) {
        int2 w = bucket[i];
        int rl = w.x >> 20;
        int p  = atomicAdd(&cur[rl], 1);
        unsigned int vb = (((unsigned int)w.y + 0x8000u) >> 16) & 0x7FFFu;
        csr[p] = (vb << 17) | (unsigned int)(w.x & 0x1FFFF);
    }
}

// ---------------------------------------------------------------------------
// SpMM v2: one wave per row, j-loop unrolled x4 -> 4 gathers in flight.
// ---------------------------------------------------------------------------
__global__ __launch_bounds__(256)
void spmm_kernel(const unsigned short* __restrict__ sup,
                 const int* __restrict__ offs, const int* __restrict__ counts,
                 const unsigned int* __restrict__ csr, float* __restrict__ out) {
    const int wave = threadIdx.x >> 6;
    const int lane = threadIdx.x & 63;
    const int row  = blockIdx.x * 4 + wave;
    if (row >= N_NODES) return;

    const int start = offs[row];
    const int deg   = counts[row];

    float a0 = 0.f, a1 = 0.f, a2 = 0.f, a3 = 0.f;

    for (int base = 0; base < deg; base += 64) {
        int nb = deg - base;
        if (nb > 64) nb = 64;
        int c = 0;
        float v = 0.f;
        if (lane < nb) {
            unsigned int w = csr[start + base + lane];
            c = (int)(w & 0x1FFFFu);
            v = __uint_as_float((w >> 17) << 16);
        }
        int j = 0;
        for (; j + 4 <= nb; j += 4) {
            int   c0 = __shfl(c, j),     c1 = __shfl(c, j + 1);
            int   c2 = __shfl(c, j + 2), c3 = __shfl(c, j + 3);
            float v0 = __shfl(v, j),     v1 = __shfl(v, j + 1);
            float v2 = __shfl(v, j + 2), v3 = __shfl(v, j + 3);
            ushort4 h0 = *(const ushort4*)(sup + (size_t)c0 * 256 + lane * 4);
            ushort4 h1 = *(const ushort4*)(sup + (size_t)c1 * 256 + lane * 4);
            ushort4 h2 = *(const ushort4*)(sup + (size_t)c2 * 256 + lane * 4);
            ushort4 h3 = *(const ushort4*)(sup + (size_t)c3 * 256 + lane * 4);
            a0 += v0 * b2f(h0.x); a1 += v0 * b2f(h0.y);
            a2 += v0 * b2f(h0.z); a3 += v0 * b2f(h0.w);
            a0 += v1 * b2f(h1.x); a1 += v1 * b2f(h1.y);
            a2 += v1 * b2f(h1.z); a3 += v1 * b2f(h1.w);
            a0 += v2 * b2f(h2.x); a1 += v2 * b2f(h2.y);
            a2 += v2 * b2f(h2.z); a3 += v2 * b2f(h2.w);
            a0 += v3 * b2f(h3.x); a1 += v3 * b2f(h3.y);
            a2 += v3 * b2f(h3.z); a3 += v3 * b2f(h3.w);
        }
        for (; j < nb; j++) {
            int   cj = __shfl(c, j);
            float vj = __shfl(v, j);
            ushort4 hh = *(const ushort4*)(sup + (size_t)cj * 256 + lane * 4);
            a0 += vj * b2f(hh.x); a1 += vj * b2f(hh.y);
            a2 += vj * b2f(hh.z); a3 += vj * b2f(hh.w);
        }
    }

    float4 o;
    o.x = a0 > 0.f ? a0 : 0.f;
    o.y = a1 > 0.f ? a1 : 0.f;
    o.z = a2 > 0.f ? a2 : 0.f;
    o.w = a3 > 0.f ? a3 : 0.f;
    *(float4*)(out + (size_t)row * 256 + lane * 4) = o;
}

// ---------------------------------------------------------------------------
extern "C" void kernel_launch(void* const* d_in, const int* in_sizes, int n_in,
                              void* d_out, int out_size, void* d_ws, size_t ws_size,
                              hipStream_t stream) {
    const float* features = (const float*)d_in[0];
    const float* weight   = (const float*)d_in[1];
    const int*   adj_row  = (const int*)d_in[2];
    const int*   adj_col  = (const int*)d_in[3];
    const float* adj_val  = (const float*)d_in[4];
    float* out = (float*)d_out;

    char* ws = (char*)d_ws;
    size_t off = 0;
    auto alloc = [&](size_t bytes) -> char* {
        char* p = ws + off;
        off = (off + bytes + 255) & ~(size_t)255;
        return p;
    };
    unsigned short* sup     = (unsigned short*)alloc((size_t)N_NODES * 256 * 2); // 51.2 MB
    unsigned short* BT      = (unsigned short*)alloc(256 * 256 * 2);
    int*            counts  = (int*)alloc((size_t)N_NODES * 4);
    int*            offsets = (int*)alloc((size_t)N_NODES * 4);
    int*            ghist   = (int*)alloc(512 * 4);
    int*            bbase   = (int*)alloc(512 * 4);
    int*            gcur    = (int*)alloc(512 * 4);
    int2*           bucket  = (int2*)alloc((size_t)N_EDGES * 8);                 // 25.6 MB
    unsigned int*   csr     = (unsigned int*)alloc((size_t)N_EDGES * 4);         // 12.8 MB

    hipMemsetAsync(ghist, 0, NBUCK * 4, stream);

    transpose_b<<<256, 256, 0, stream>>>(weight, BT);
    gemm_dma<<<782, 512, 0, stream>>>(features, BT, sup);          // ceil(100000/128)
    bhist_kernel<<<782, 256, 0, stream>>>(adj_row, ghist);         // ceil(3.2M/4096)
    bscan_kernel<<<1, 512, 0, stream>>>(ghist, bbase, gcur);
    bin_kernel<<<782, 256, 0, stream>>>(adj_row, adj_col, adj_val, gcur, bucket);
    csort_kernel<<<NBUCK, 256, 0, stream>>>(bucket, bbase, gcur, csr, offsets, counts);
    spmm_kernel<<<25000, 256, 0, stream>>>(sup, offsets, counts, csr, out);
}